// Round 5
// baseline (3736.151 us; speedup 1.0000x reference)
//
#include <hip/hip_runtime.h>

// B=64, IN=1024, OUT=1024, T=256
// syn[b,o,t] = sum_i W[o,i]*x[b,i,t], f64 accumulation on the VALU
// (f32*f32 products exact in f64). Stored as double-f32 (hi->d_out,
// lo->d_ws); f64 LIF scan writes f32 spikes into d_out in place.
//
// R4 NOTE: f64 MFMA (v_mfma_f64_16x16x4) with textbook CDNA2 layouts FAILED
// correctness on gfx950 — f64 fragment layout is NOT covered by the measured
// dtype-independence results. Do not retry blind.
//
// R5: proven R3 vector structure (8x8 f64 micro-tile, 128x128 block) with the
// two diagnosed fixes:
//  - LDS staged in f64: 16 cvt/thread/k-tile instead of 256 (R3: cvt was ~30%
//    of VALU -> capped at 43 TF).
//  - B tile group-padded 8->9 doubles (pitch 144): fragment-read lane stride
//    72 B -> 16 distinct even start banks -> <=2-way (was 8-way at 64 B).
//  A-fragment reads are 16-lane broadcast (free), pitch 130.

#define B_DIM 64
#define IN_DIM 1024
#define OUT_DIM 1024
#define T_DIM 256

#define BM 128   // o
#define BN 128   // t
#define BK 16    // k
#define LDA 130  // A row pitch (doubles)
#define LDB 144  // B row pitch (doubles): 16 groups x 9

typedef double v4d __attribute__((ext_vector_type(4)));

__global__ __launch_bounds__(256, 2) void spk_gemm_f64v2_kernel(
    const float* __restrict__ x,    // [B, IN, T]
    const float* __restrict__ W,    // [OUT, IN]
    float* __restrict__ syn_hi,     // [B, OUT, T] = d_out
    float* __restrict__ syn_lo)     // [B, OUT, T] = d_ws
{
    const int tid = threadIdx.x;
    const int tb = blockIdx.x;   // t tile: 0..1
    const int ob = blockIdx.y;   // o tile: 0..7
    const int b  = blockIdx.z;   // batch:  0..63

    __shared__ __align__(16) double As[BK][LDA];  // W tile, [k][o]
    __shared__ __align__(16) double Bs[BK][LDB];  // x tile, [k][group*9+e]

    const int o0 = ob * BM;
    const int t0 = tb * BN;

    const float* Wp = W + (size_t)o0 * IN_DIM;
    const float* xp = x + (size_t)b * IN_DIM * T_DIM + t0;

    double acc[8][8] = {};

    const int ro  = (tid / 16) * 8;  // micro-tile row base (o): 0..120
    const int cog = tid % 16;        // micro-tile t-group: global t = cog*8+j

    // A staging: 128 rows x 16 k = 512 float4 -> 2/thread
    const int ar0 = tid / 4;             // o row (+64 for p=1)
    const int ac  = (tid % 4) * 4;       // k col
    // B staging: 16 k x 128 t = 512 float4 -> 2/thread
    const int bkr0 = tid / 32;           // k row (+8 for p=1)
    const int btc  = (tid % 32) * 4;     // t col (mult of 4, within one group)
    const int bpos = (btc >> 3) * 9 + (btc & 7);  // group-padded LDS position

    float4 pa[2], pb[2];
    #pragma unroll
    for (int p = 0; p < 2; ++p) {   // preload k-tile 0
        pa[p] = *(const float4*)&Wp[(size_t)(ar0 + p * 64) * IN_DIM + ac];
        pb[p] = *(const float4*)&xp[(size_t)(bkr0 + p * 8) * T_DIM + btc];
    }

    for (int k0 = 0; k0 < IN_DIM; k0 += BK) {
        // stage regs -> LDS, converting f32->f64 once per k-tile
        #pragma unroll
        for (int p = 0; p < 2; ++p) {
            const int r = ar0 + p * 64;
            As[ac + 0][r] = (double)pa[p].x;
            As[ac + 1][r] = (double)pa[p].y;
            As[ac + 2][r] = (double)pa[p].z;
            As[ac + 3][r] = (double)pa[p].w;
            const int kr = bkr0 + p * 8;
            Bs[kr][bpos + 0] = (double)pb[p].x;
            Bs[kr][bpos + 1] = (double)pb[p].y;
            Bs[kr][bpos + 2] = (double)pb[p].z;
            Bs[kr][bpos + 3] = (double)pb[p].w;
        }
        // prefetch next k-tile (latency hides under the FMA phase)
        if (k0 + BK < IN_DIM) {
            #pragma unroll
            for (int p = 0; p < 2; ++p) {
                pa[p] = *(const float4*)&Wp[(size_t)(ar0 + p * 64) * IN_DIM + k0 + BK + ac];
                pb[p] = *(const float4*)&xp[(size_t)(bkr0 + p * 8 + k0 + BK) * T_DIM + btc];
            }
        }
        __syncthreads();

        #pragma unroll
        for (int kk = 0; kk < BK; ++kk) {
            // A: 2x b128-able (16-B aligned, 16-lane broadcast -> free)
            const v4d* ap = (const v4d*)&As[kk][ro];
            const v4d alo = ap[0], ahi = ap[1];
            const double a[8] = {alo[0], alo[1], alo[2], alo[3],
                                 ahi[0], ahi[1], ahi[2], ahi[3]};
            // B: 8 doubles at 72-B lane stride (conflict-free by group pad)
            const double* bp = &Bs[kk][cog * 9];
            double bb[8];
            #pragma unroll
            for (int j = 0; j < 8; ++j) bb[j] = bp[j];
            #pragma unroll
            for (int i = 0; i < 8; ++i)
                #pragma unroll
                for (int j = 0; j < 8; ++j)
                    acc[i][j] = fma(a[i], bb[j], acc[i][j]);
        }
        __syncthreads();
    }

    // Epilogue: rows ro..ro+7, cols cog*8..cog*8+7; float4 hi/lo stores.
    float* ohi = syn_hi + ((size_t)b * OUT_DIM + o0) * T_DIM + t0;
    float* olo = syn_lo + ((size_t)b * OUT_DIM + o0) * T_DIM + t0;
    #pragma unroll
    for (int i = 0; i < 8; ++i) {
        const size_t rowoff = (size_t)(ro + i) * T_DIM + cog * 8;
        #pragma unroll
        for (int jq = 0; jq < 8; jq += 4) {
            float4 h, l;
            float* hp = (float*)&h;
            float* lp = (float*)&l;
            #pragma unroll
            for (int j = 0; j < 4; ++j) {
                const double s = acc[i][jq + j];
                const float hi = (float)s;
                hp[j] = hi;
                lp[j] = (float)(s - (double)hi);
            }
            *(float4*)&ohi[rowoff + jq] = h;
            *(float4*)&olo[rowoff + jq] = l;
        }
    }
}

// In-place over hi: syn_hi on entry, f32 spikes on exit.
// f64 LIF: reset=(mem>1); mem=0.9*mem+(hi+lo)-reset; spk=(mem-1>0)
__global__ __launch_bounds__(256) void spk_scan_f64_kernel(
    float* __restrict__ hi, const float* __restrict__ lo)
{
    const int TC = 16;
    __shared__ float thi[256][TC + 1];
    __shared__ float tlo[256][TC + 1];

    const int tid = threadIdx.x;
    const size_t row0 = (size_t)blockIdx.x * 256;

    double mem = 0.0;
    for (int t0 = 0; t0 < T_DIM; t0 += TC) {
        #pragma unroll
        for (int p = 0; p < 4; ++p) {
            int id = tid + p * 256;
            int r = id / 4;
            int c = (id % 4) * 4;
            size_t g = (row0 + r) * T_DIM + t0 + c;
            float4 vh = *(const float4*)&hi[g];
            thi[r][c] = vh.x; thi[r][c+1] = vh.y; thi[r][c+2] = vh.z; thi[r][c+3] = vh.w;
            float4 vl = *(const float4*)&lo[g];
            tlo[r][c] = vl.x; tlo[r][c+1] = vl.y; tlo[r][c+2] = vl.z; tlo[r][c+3] = vl.w;
        }
        __syncthreads();

        float spk[TC];
        #pragma unroll
        for (int t = 0; t < TC; ++t) {
            double s = (double)thi[tid][t] + (double)tlo[tid][t];
            double reset = (mem > 1.0) ? 1.0 : 0.0;
            mem = 0.9 * mem + s - reset;
            spk[t] = ((mem - 1.0) > 0.0) ? 1.0f : 0.0f;
        }
        __syncthreads();

        #pragma unroll
        for (int t = 0; t < TC; ++t) thi[tid][t] = spk[t];
        __syncthreads();

        #pragma unroll
        for (int p = 0; p < 4; ++p) {
            int id = tid + p * 256;
            int r = id / 4;
            int c = (id % 4) * 4;
            float4 v = make_float4(thi[r][c], thi[r][c+1], thi[r][c+2], thi[r][c+3]);
            *(float4*)&hi[(row0 + r) * T_DIM + t0 + c] = v;
        }
        __syncthreads();
    }
}

extern "C" void kernel_launch(void* const* d_in, const int* in_sizes, int n_in,
                              void* d_out, int out_size, void* d_ws, size_t ws_size,
                              hipStream_t stream)
{
    const float* x = (const float*)d_in[0];   // [64, 1024, 256]
    const float* W = (const float*)d_in[1];   // [1024, 1024]
    float* hi = (float*)d_out;                // [64, 1024, 256]
    float* lo = (float*)d_ws;                 // 67 MB of ws

    dim3 ggrid(T_DIM / BN, OUT_DIM / BM, B_DIM);  // (2, 8, 64)
    spk_gemm_f64v2_kernel<<<ggrid, dim3(256), 0, stream>>>(x, W, hi, lo);

    dim3 sgrid((B_DIM * OUT_DIM) / 256);          // 256 blocks
    spk_scan_f64_kernel<<<sgrid, dim3(256), 0, stream>>>(hi, lo);
}

// Round 6
// 644.799 us; speedup vs baseline: 5.7943x; 5.7943x over previous
//
#include <hip/hip_runtime.h>

// B=64, IN=1024, OUT=1024, T=256
// syn[b,o,t] = sum_i W[o,i]*x[b,i,t], exact f64 accumulation via
// v_mfma_f64_16x16x4_f64. Stored as double-f32 (hi->d_out, lo->d_ws);
// f64 LIF scan writes f32 spikes into d_out in place.
//
// History: R3 vector-f64 = 805 us (VALU-capped, acc can't fit 2 waves/SIMD).
// R5 8x8 vector tile SPILLED (acc alone = 256 VGPRs) -> 3.7 ms scratch storm.
// R4 MFMA failed on a blind f64 fragment-layout guess.
// R6: MFMA with RUNTIME LAYOUT PROBES — two exact-integer f64 MFMAs decode
// (a) A lane-map, (b) B lane-map, (c) per-register D row indices. Only axiom:
// D col = lane&15 (measured dtype-independent on gfx950, 7 dtypes).

#define B_DIM 64
#define IN_DIM 1024
#define OUT_DIM 1024
#define T_DIM 256

#define BM 128   // o
#define BN 128   // t
#define BK 16    // k (4 MFMA k-steps)
#define LDA 130  // LDS row pitch in doubles

typedef double v4d __attribute__((ext_vector_type(4)));

__global__ __launch_bounds__(256, 2) void spk_gemm_mfma64p_kernel(
    const float* __restrict__ x,    // [B, IN, T]
    const float* __restrict__ W,    // [OUT, IN]
    float* __restrict__ syn_hi,     // [B, OUT, T] = d_out
    float* __restrict__ syn_lo)     // [B, OUT, T] = d_ws
{
    const int tid  = threadIdx.x;
    const int lane = tid & 63;
    const int wave = tid >> 6;

    const int tb = blockIdx.x;   // t tile: 0..1
    const int ob = blockIdx.y;   // o tile: 0..7
    const int b  = blockIdx.z;   // batch:  0..63

    __shared__ __align__(16) double As[BK][LDA];  // W tile, [k][o]
    __shared__ __align__(16) double Bs[BK][LDA];  // x tile, [k][t]

    // ---- Runtime MFMA layout probe (exact small-int f64 arithmetic) ----
    // P1: a=lane, b=1  -> D[m][n] = rowsum(A).
    //   map H1 (m=l&15,k=l>>4): rowsum = 4m+96  (== 0 mod 4)
    //   map H2 (m=l>>2,k=l&3):  rowsum = 16m+6  (== 2 mod 4)
    // P2: a=1, b=lane -> D[m][n] = colsum(B), same decode with n = lane&15.
    const v4d zz = {0.0, 0.0, 0.0, 0.0};
    v4d d1 = __builtin_amdgcn_mfma_f64_16x16x4f64((double)lane, 1.0, zz, 0, 0, 0);
    v4d d2 = __builtin_amdgcn_mfma_f64_16x16x4f64(1.0, (double)lane, zz, 0, 0, 0);

    const bool a_h1 = (((int)d1[0] & 3) == 0);
    const bool b_h1 = (((int)d2[0] & 3) == 0);
    int drow[4];
    #pragma unroll
    for (int r = 0; r < 4; ++r) {
        const int v = (int)d1[r];
        drow[r] = (a_h1 ? (v - 96) >> 2 : (v - 6) >> 4) & 15;  // D row of reg r
    }
    const int am = a_h1 ? (lane & 15) : (lane >> 2);  // A element row (m)
    const int ak = a_h1 ? (lane >> 4) : (lane & 3);   // A element k within step
    const int bn = b_h1 ? (lane & 15) : (lane >> 2);  // B element col (n)
    const int bk = b_h1 ? (lane >> 4) : (lane & 3);   // B element k within step
    const int dcol = lane & 15;                       // D col (measured axiom)
    // --------------------------------------------------------------------

    const int o0 = ob * BM;
    const int t0 = tb * BN;

    const float* Wp = W + (size_t)o0 * IN_DIM;
    const float* xp = x + (size_t)b * IN_DIM * T_DIM + t0;

    // wave quadrant: 64(o) x 64(t)
    const int wo = (wave >> 1) * 64;
    const int wt = (wave & 1) * 64;

    v4d acc[4][4];
    #pragma unroll
    for (int i = 0; i < 4; ++i)
        #pragma unroll
        for (int j = 0; j < 4; ++j)
            acc[i][j] = zz;

    // Staging (proven in R5): 2 float4 of W + 2 float4 of x per thread/k-tile
    const int ar0 = tid / 4;             // o row (+64 for p=1)
    const int ac  = (tid % 4) * 4;       // k col
    const int bkr0 = tid / 32;           // k row (+8 for p=1)
    const int btc  = (tid % 32) * 4;     // t col

    float4 pa[2], pb[2];
    #pragma unroll
    for (int p = 0; p < 2; ++p) {   // preload k-tile 0
        pa[p] = *(const float4*)&Wp[(size_t)(ar0 + p * 64) * IN_DIM + ac];
        pb[p] = *(const float4*)&xp[(size_t)(bkr0 + p * 8) * T_DIM + btc];
    }

    for (int k0 = 0; k0 < IN_DIM; k0 += BK) {
        // stage regs -> LDS (one f32->f64 convert per element)
        #pragma unroll
        for (int p = 0; p < 2; ++p) {
            const int r = ar0 + p * 64;
            As[ac + 0][r] = (double)pa[p].x;
            As[ac + 1][r] = (double)pa[p].y;
            As[ac + 2][r] = (double)pa[p].z;
            As[ac + 3][r] = (double)pa[p].w;
            const int kr = bkr0 + p * 8;
            Bs[kr][btc + 0] = (double)pb[p].x;
            Bs[kr][btc + 1] = (double)pb[p].y;
            Bs[kr][btc + 2] = (double)pb[p].z;
            Bs[kr][btc + 3] = (double)pb[p].w;
        }
        // prefetch next k-tile into registers (hides under MFMA phase)
        if (k0 + BK < IN_DIM) {
            #pragma unroll
            for (int p = 0; p < 2; ++p) {
                pa[p] = *(const float4*)&Wp[(size_t)(ar0 + p * 64) * IN_DIM + k0 + BK + ac];
                pb[p] = *(const float4*)&xp[(size_t)(bkr0 + p * 8 + k0 + BK) * T_DIM + btc];
            }
        }
        __syncthreads();

        #pragma unroll
        for (int kk = 0; kk < 4; ++kk) {
            const int kra = kk * 4 + ak;
            const int krb = kk * 4 + bk;
            double a[4], bb[4];
            #pragma unroll
            for (int i = 0; i < 4; ++i) a[i] = As[kra][wo + i * 16 + am];
            #pragma unroll
            for (int j = 0; j < 4; ++j) bb[j] = Bs[krb][wt + j * 16 + bn];
            #pragma unroll
            for (int i = 0; i < 4; ++i)
                #pragma unroll
                for (int j = 0; j < 4; ++j)
                    acc[i][j] = __builtin_amdgcn_mfma_f64_16x16x4f64(
                        a[i], bb[j], acc[i][j], 0, 0, 0);
        }
        __syncthreads();
    }

    // Epilogue with probed D row map
    float* ohi = syn_hi + ((size_t)b * OUT_DIM + o0) * T_DIM + t0;
    float* olo = syn_lo + ((size_t)b * OUT_DIM + o0) * T_DIM + t0;
    #pragma unroll
    for (int i = 0; i < 4; ++i) {
        #pragma unroll
        for (int j = 0; j < 4; ++j) {
            const int col = wt + j * 16 + dcol;
            #pragma unroll
            for (int r = 0; r < 4; ++r) {
                const double s = acc[i][j][r];
                const float hi = (float)s;
                const float lo = (float)(s - (double)hi);
                const size_t off = (size_t)(wo + i * 16 + drow[r]) * T_DIM + col;
                ohi[off] = hi;
                olo[off] = lo;
            }
        }
    }
}

// In-place over hi: syn_hi on entry, f32 spikes on exit. (Proven R2/R3/R5.)
// f64 LIF: reset=(mem>1); mem=0.9*mem+(hi+lo)-reset; spk=(mem-1>0)
__global__ __launch_bounds__(256) void spk_scan_f64_kernel(
    float* __restrict__ hi, const float* __restrict__ lo)
{
    const int TC = 16;
    __shared__ float thi[256][TC + 1];
    __shared__ float tlo[256][TC + 1];

    const int tid = threadIdx.x;
    const size_t row0 = (size_t)blockIdx.x * 256;

    double mem = 0.0;
    for (int t0 = 0; t0 < T_DIM; t0 += TC) {
        #pragma unroll
        for (int p = 0; p < 4; ++p) {
            int id = tid + p * 256;
            int r = id / 4;
            int c = (id % 4) * 4;
            size_t g = (row0 + r) * T_DIM + t0 + c;
            float4 vh = *(const float4*)&hi[g];
            thi[r][c] = vh.x; thi[r][c+1] = vh.y; thi[r][c+2] = vh.z; thi[r][c+3] = vh.w;
            float4 vl = *(const float4*)&lo[g];
            tlo[r][c] = vl.x; tlo[r][c+1] = vl.y; tlo[r][c+2] = vl.z; tlo[r][c+3] = vl.w;
        }
        __syncthreads();

        float spk[TC];
        #pragma unroll
        for (int t = 0; t < TC; ++t) {
            double s = (double)thi[tid][t] + (double)tlo[tid][t];
            double reset = (mem > 1.0) ? 1.0 : 0.0;
            mem = 0.9 * mem + s - reset;
            spk[t] = ((mem - 1.0) > 0.0) ? 1.0f : 0.0f;
        }
        __syncthreads();

        #pragma unroll
        for (int t = 0; t < TC; ++t) thi[tid][t] = spk[t];
        __syncthreads();

        #pragma unroll
        for (int p = 0; p < 4; ++p) {
            int id = tid + p * 256;
            int r = id / 4;
            int c = (id % 4) * 4;
            float4 v = make_float4(thi[r][c], thi[r][c+1], thi[r][c+2], thi[r][c+3]);
            *(float4*)&hi[(row0 + r) * T_DIM + t0 + c] = v;
        }
        __syncthreads();
    }
}

extern "C" void kernel_launch(void* const* d_in, const int* in_sizes, int n_in,
                              void* d_out, int out_size, void* d_ws, size_t ws_size,
                              hipStream_t stream)
{
    const float* x = (const float*)d_in[0];   // [64, 1024, 256]
    const float* W = (const float*)d_in[1];   // [1024, 1024]
    float* hi = (float*)d_out;                // [64, 1024, 256]
    float* lo = (float*)d_ws;                 // 67 MB of ws

    dim3 ggrid(T_DIM / BN, OUT_DIM / BM, B_DIM);  // (2, 8, 64)
    spk_gemm_mfma64p_kernel<<<ggrid, dim3(256), 0, stream>>>(x, W, hi, lo);

    dim3 sgrid((B_DIM * OUT_DIM) / 256);          // 256 blocks
    spk_scan_f64_kernel<<<sgrid, dim3(256), 0, stream>>>(hi, lo);
}

// Round 7
// 573.508 us; speedup vs baseline: 6.5146x; 1.1243x over previous
//
#include <hip/hip_runtime.h>

// B=64, IN=1024, OUT=1024, T=256
// syn[b,o,t] = sum_i W[o,i]*x[b,i,t]; spikes via f64 LIF scan.
//
// R7: Ozaki int8 slicing. W rows scaled by 2^-ea (frexp of row max), x cols
// (b,t) by 2^-eb; 6 signed 7-bit digits each (exact truncated base-128).
// 26 i8 MFMAs (pairs p+q<=6) per k-32 accumulate EXACTLY in i32 groups S_s;
// syn = 2^(ea+eb) * sum_s S_s*2^{-7(s+2)} in f64 (error ~2e-10, spike-safe).
// i8 MFMA layout risk handled by runtime probes (R6 technique).
// Fallback (ws too small): R6 f64-MFMA path (645 us, proven).

#define B_DIM 64
#define IN_DIM 1024
#define OUT_DIM 1024
#define T_DIM 256

typedef int v4i __attribute__((ext_vector_type(4)));
typedef int v16i __attribute__((ext_vector_type(16)));
typedef double v4d __attribute__((ext_vector_type(4)));

// ---------------- workspace layout (bytes) ----------------
#define LO_OFF   0ull                    // 67108864  f32 syn_lo
#define WSL_OFF  67108864ull             // 6291456   i8  W slices [6][1024][1024]
#define XSL_OFF  73400320ull             // 100663296 i8  x slices [6][64][256][1024] (t-major, i-contig)
#define AL_OFF   174063616ull            // 4096      i32 alpha_e[1024]
#define BE_OFF   174067712ull            // 65536     i32 beta_e[64][256]
#define PART_OFF 174133248ull            // 1048576   f32 partial maxes [64][16][256]
#define WS_NEED  175181824ull

// ---------------- K1a: partial column maxes ----------------
__global__ __launch_bounds__(256) void k_beta_part(const float* __restrict__ x,
                                                   float* __restrict__ part)
{
    const int ic = blockIdx.x;   // i chunk 0..15
    const int b  = blockIdx.y;
    const int t  = threadIdx.x;
    const float* p = x + ((size_t)b * IN_DIM + ic * 64) * T_DIM + t;
    float m = 0.f;
    #pragma unroll 4
    for (int i = 0; i < 64; ++i) m = fmaxf(m, fabsf(p[(size_t)i * T_DIM]));
    part[((size_t)b * 16 + ic) * T_DIM + t] = m;
}

// ---------------- K1b: beta exponents ----------------
__global__ __launch_bounds__(256) void k_beta(const float* __restrict__ part,
                                              int* __restrict__ beta_e)
{
    const int b = blockIdx.x, t = threadIdx.x;
    float m = 0.f;
    #pragma unroll
    for (int ic = 0; ic < 16; ++ic)
        m = fmaxf(m, part[((size_t)b * 16 + ic) * T_DIM + t]);
    int e = 0;
    if (m > 0.f) frexpf(m, &e);   // m = f*2^e, f in [0.5,1) -> |x|/2^e < 1
    beta_e[b * T_DIM + t] = e;
}

// ---------------- K2: slice + transpose x -> xsl[p][b][t][i] ----------------
__global__ __launch_bounds__(256) void k_slice_x(const float* __restrict__ x,
    const int* __restrict__ beta_e, signed char* __restrict__ xsl)
{
    __shared__ float ft[64][65];
    const int tb = blockIdx.x;    // t tile 0..3
    const int ib = blockIdx.y;    // i tile 0..15
    const int b  = blockIdx.z;
    const int tid = threadIdx.x;
    const int t0 = tb * 64, i0 = ib * 64;
    #pragma unroll
    for (int p = 0; p < 16; ++p) {
        int id = tid + p * 256;
        int il = id >> 6, tl = id & 63;
        ft[il][tl] = x[((size_t)b * IN_DIM + i0 + il) * T_DIM + t0 + tl];
    }
    __syncthreads();
    const int tl = tid >> 2;
    const int iq = (tid & 3) * 16;
    const int e = beta_e[b * T_DIM + t0 + tl];
    signed char dig[16][6];
    #pragma unroll
    for (int j = 0; j < 16; ++j) {
        double r = ldexp((double)ft[iq + j][tl], -e);  // exact dyadic
        #pragma unroll
        for (int p = 0; p < 6; ++p) {
            r *= 128.0;              // exact
            double d = trunc(r);     // digit in [-127,127]
            r -= d;                  // exact
            dig[j][p] = (signed char)(int)d;
        }
    }
    #pragma unroll
    for (int p = 0; p < 6; ++p) {
        size_t base = (((size_t)p * B_DIM + b) * T_DIM + t0 + tl) * IN_DIM + i0 + iq;
        #pragma unroll
        for (int g = 0; g < 4; ++g) {
            int w = (dig[4*g][p] & 0xff) | ((dig[4*g+1][p] & 0xff) << 8) |
                    ((dig[4*g+2][p] & 0xff) << 16) | ((dig[4*g+3][p] & 0xff) << 24);
            *(int*)&xsl[base + 4 * g] = w;
        }
    }
}

// ---------------- K3: alpha + slice W -> wsl[p][o][i] ----------------
__global__ __launch_bounds__(256) void k_slice_w(const float* __restrict__ W,
    signed char* __restrict__ wsl, int* __restrict__ alpha_e)
{
    __shared__ float red[256];
    __shared__ int se;
    const int o = blockIdx.x, tid = threadIdx.x;
    float4 v = *(const float4*)&W[(size_t)o * IN_DIM + tid * 4];
    float m = fmaxf(fmaxf(fabsf(v.x), fabsf(v.y)), fmaxf(fabsf(v.z), fabsf(v.w)));
    red[tid] = m; __syncthreads();
    for (int s = 128; s > 0; s >>= 1) {
        if (tid < s) red[tid] = fmaxf(red[tid], red[tid + s]);
        __syncthreads();
    }
    if (tid == 0) { int e = 0; if (red[0] > 0.f) frexpf(red[0], &e); se = e; alpha_e[o] = e; }
    __syncthreads();
    const int e = se;
    float vv[4] = {v.x, v.y, v.z, v.w};
    signed char dig[4][6];
    #pragma unroll
    for (int j = 0; j < 4; ++j) {
        double r = ldexp((double)vv[j], -e);
        #pragma unroll
        for (int p = 0; p < 6; ++p) { r *= 128.0; double d = trunc(r); r -= d; dig[j][p] = (signed char)(int)d; }
    }
    #pragma unroll
    for (int p = 0; p < 6; ++p) {
        int w = (dig[0][p] & 0xff) | ((dig[1][p] & 0xff) << 8) |
                ((dig[2][p] & 0xff) << 16) | ((dig[3][p] & 0xff) << 24);
        *(int*)&wsl[((size_t)p * OUT_DIM + o) * IN_DIM + tid * 4] = w;
    }
}

// ---------------- K4: Ozaki i8 MFMA GEMM ----------------
// Block 64(o)x64(t), 4 waves 2x2 of 32x32 tiles, BK=64 (2 MFMA k-steps).
// LDS row stride 80 B (64 data + 16 pad -> 8 lanes cover all 32 banks on b128).
#define OZ_SLS (64 * 80)   // per-slice LDS bytes

__global__ __launch_bounds__(256, 2) void k_oz_gemm(
    const signed char* __restrict__ wsl, const signed char* __restrict__ xsl,
    const int* __restrict__ alpha_e, const int* __restrict__ beta_e,
    float* __restrict__ syn_hi, float* __restrict__ syn_lo)
{
    __shared__ __align__(16) signed char As[6 * OZ_SLS];
    __shared__ __align__(16) signed char Bs[6 * OZ_SLS];

    const int tid = threadIdx.x;
    const int lane = tid & 63, wave = tid >> 6;
    const int tb = blockIdx.x;   // 0..3
    const int ob = blockIdx.y;   // 0..15
    const int b  = blockIdx.z;
    const int o0 = ob * 64, t0 = tb * 64;
    const int wo = (wave >> 1) * 32, wt = (wave & 1) * 32;
    const int lr = lane & 31, kh = lane >> 5;

    v16i acc[7];
    #pragma unroll
    for (int s = 0; s < 7; ++s)
        acc[s] = (v16i){0,0,0,0,0,0,0,0,0,0,0,0,0,0,0,0};

    // staging: per slice p, thread stages one 16B unit: row=tid>>2, u=tid&3
    const int srow = tid >> 2, su = tid & 3;
    const size_t wbase = ((size_t)o0 + srow) * IN_DIM + su * 16;
    const size_t xbase = ((size_t)b * T_DIM + t0 + srow) * IN_DIM + su * 16;
    const int ldso = srow * 80 + su * 16;

    v4i pa[6], pb[6];
    #pragma unroll
    for (int p = 0; p < 6; ++p) {
        pa[p] = *(const v4i*)(wsl + ((size_t)p << 20) + wbase);
        pb[p] = *(const v4i*)(xsl + ((size_t)p << 24) + xbase);
    }

    for (int k0 = 0; k0 < IN_DIM; k0 += 64) {
        #pragma unroll
        for (int p = 0; p < 6; ++p) {
            *(v4i*)(As + p * OZ_SLS + ldso) = pa[p];
            *(v4i*)(Bs + p * OZ_SLS + ldso) = pb[p];
        }
        if (k0 + 64 < IN_DIM) {
            #pragma unroll
            for (int p = 0; p < 6; ++p) {
                pa[p] = *(const v4i*)(wsl + ((size_t)p << 20) + wbase + k0 + 64);
                pb[p] = *(const v4i*)(xsl + ((size_t)p << 24) + xbase + k0 + 64);
            }
        }
        __syncthreads();

        #pragma unroll
        for (int ks = 0; ks < 2; ++ks) {
            const int fo = ks * 32 + kh * 16;
            v4i bf[6];
            #pragma unroll
            for (int q = 0; q < 6; ++q)
                bf[q] = *(const v4i*)(Bs + q * OZ_SLS + (wt + lr) * 80 + fo);
            #pragma unroll
            for (int p = 0; p < 6; ++p) {
                v4i af = *(const v4i*)(As + p * OZ_SLS + (wo + lr) * 80 + fo);
                #pragma unroll
                for (int q = 0; q < 6; ++q) {
                    if (p + q <= 6)
                        acc[p + q] = __builtin_amdgcn_mfma_i32_32x32x32_i8(
                            af, bf[q], acc[p + q], 0, 0, 0);
                }
            }
        }
        __syncthreads();
    }

    // Runtime placement probes (R6 technique): decode D row/col under our
    // staging convention. P1: A bytes=(row+1), B=1 -> D = 32*(row_owner+1).
    const int rv = (lr + 1) * 0x01010101;
    const v4i pav  = {rv, rv, rv, rv};
    const v4i onev = {0x01010101, 0x01010101, 0x01010101, 0x01010101};
    const v16i z = (v16i){0,0,0,0,0,0,0,0,0,0,0,0,0,0,0,0};
    v16i d1 = __builtin_amdgcn_mfma_i32_32x32x32_i8(pav, onev, z, 0, 0, 0);
    v16i d2 = __builtin_amdgcn_mfma_i32_32x32x32_i8(onev, pav, z, 0, 0, 0);

    const int col = (d2[0] >> 5) - 1;            // 0..31 within tile
    const int gt = t0 + wt + col;
    const int eb = beta_e[b * T_DIM + gt];
    float* ohi = syn_hi + ((size_t)b * OUT_DIM + o0) * T_DIM + gt;
    float* olo = syn_lo + ((size_t)b * OUT_DIM + o0) * T_DIM + gt;

    const double C0 = 0x1p-14, C1 = 0x1p-21, C2 = 0x1p-28, C3 = 0x1p-35,
                 C4 = 0x1p-42, C5 = 0x1p-49, C6 = 0x1p-56;
    #pragma unroll
    for (int r = 0; r < 16; ++r) {
        const int row = (d1[r] >> 5) - 1;        // 0..31 within tile
        const int go = wo + row;
        const int ea = alpha_e[o0 + go];
        double v = (double)acc[0][r] * C0 + (double)acc[1][r] * C1 +
                   (double)acc[2][r] * C2 + (double)acc[3][r] * C3 +
                   (double)acc[4][r] * C4 + (double)acc[5][r] * C5 +
                   (double)acc[6][r] * C6;
        double syn = ldexp(v, ea + eb);
        float hi = (float)syn;
        float lo = (float)(syn - (double)hi);
        ohi[(size_t)go * T_DIM] = hi;
        olo[(size_t)go * T_DIM] = lo;
    }
}

// ---------------- Fallback GEMM: R6 f64-MFMA with probes (proven, 581 us) ----
#define BM 128
#define BN 128
#define BK 16
#define LDA 130

__global__ __launch_bounds__(256, 2) void spk_gemm_mfma64p_kernel(
    const float* __restrict__ x, const float* __restrict__ W,
    float* __restrict__ syn_hi, float* __restrict__ syn_lo)
{
    const int tid  = threadIdx.x;
    const int lane = tid & 63;
    const int wave = tid >> 6;
    const int tb = blockIdx.x, ob = blockIdx.y, b = blockIdx.z;

    __shared__ __align__(16) double As[BK][LDA];
    __shared__ __align__(16) double Bs[BK][LDA];

    const v4d zz = {0.0, 0.0, 0.0, 0.0};
    v4d d1 = __builtin_amdgcn_mfma_f64_16x16x4f64((double)lane, 1.0, zz, 0, 0, 0);
    v4d d2 = __builtin_amdgcn_mfma_f64_16x16x4f64(1.0, (double)lane, zz, 0, 0, 0);
    const bool a_h1 = (((int)d1[0] & 3) == 0);
    const bool b_h1 = (((int)d2[0] & 3) == 0);
    int drow[4];
    #pragma unroll
    for (int r = 0; r < 4; ++r) {
        const int v = (int)d1[r];
        drow[r] = (a_h1 ? (v - 96) >> 2 : (v - 6) >> 4) & 15;
    }
    const int am = a_h1 ? (lane & 15) : (lane >> 2);
    const int ak = a_h1 ? (lane >> 4) : (lane & 3);
    const int bn = b_h1 ? (lane & 15) : (lane >> 2);
    const int bk = b_h1 ? (lane >> 4) : (lane & 3);
    const int dcol = lane & 15;

    const int o0 = ob * BM, t0 = tb * BN;
    const float* Wp = W + (size_t)o0 * IN_DIM;
    const float* xp = x + (size_t)b * IN_DIM * T_DIM + t0;
    const int wo = (wave >> 1) * 64, wt = (wave & 1) * 64;

    v4d acc[4][4];
    #pragma unroll
    for (int i = 0; i < 4; ++i)
        #pragma unroll
        for (int j = 0; j < 4; ++j) acc[i][j] = zz;

    const int ar0 = tid / 4, ac = (tid % 4) * 4;
    const int bkr0 = tid / 32, btc = (tid % 32) * 4;

    float4 pa[2], pb[2];
    #pragma unroll
    for (int p = 0; p < 2; ++p) {
        pa[p] = *(const float4*)&Wp[(size_t)(ar0 + p * 64) * IN_DIM + ac];
        pb[p] = *(const float4*)&xp[(size_t)(bkr0 + p * 8) * T_DIM + btc];
    }

    for (int k0 = 0; k0 < IN_DIM; k0 += BK) {
        #pragma unroll
        for (int p = 0; p < 2; ++p) {
            const int r = ar0 + p * 64;
            As[ac + 0][r] = (double)pa[p].x; As[ac + 1][r] = (double)pa[p].y;
            As[ac + 2][r] = (double)pa[p].z; As[ac + 3][r] = (double)pa[p].w;
            const int kr = bkr0 + p * 8;
            Bs[kr][btc + 0] = (double)pb[p].x; Bs[kr][btc + 1] = (double)pb[p].y;
            Bs[kr][btc + 2] = (double)pb[p].z; Bs[kr][btc + 3] = (double)pb[p].w;
        }
        if (k0 + BK < IN_DIM) {
            #pragma unroll
            for (int p = 0; p < 2; ++p) {
                pa[p] = *(const float4*)&Wp[(size_t)(ar0 + p * 64) * IN_DIM + k0 + BK + ac];
                pb[p] = *(const float4*)&xp[(size_t)(bkr0 + p * 8 + k0 + BK) * T_DIM + btc];
            }
        }
        __syncthreads();
        #pragma unroll
        for (int kk = 0; kk < 4; ++kk) {
            const int kra = kk * 4 + ak, krb = kk * 4 + bk;
            double a[4], bb[4];
            #pragma unroll
            for (int i = 0; i < 4; ++i) a[i] = As[kra][wo + i * 16 + am];
            #pragma unroll
            for (int j = 0; j < 4; ++j) bb[j] = Bs[krb][wt + j * 16 + bn];
            #pragma unroll
            for (int i = 0; i < 4; ++i)
                #pragma unroll
                for (int j = 0; j < 4; ++j)
                    acc[i][j] = __builtin_amdgcn_mfma_f64_16x16x4f64(a[i], bb[j], acc[i][j], 0, 0, 0);
        }
        __syncthreads();
    }

    float* ohi = syn_hi + ((size_t)b * OUT_DIM + o0) * T_DIM + t0;
    float* olo = syn_lo + ((size_t)b * OUT_DIM + o0) * T_DIM + t0;
    #pragma unroll
    for (int i = 0; i < 4; ++i)
        #pragma unroll
        for (int j = 0; j < 4; ++j) {
            const int col = wt + j * 16 + dcol;
            #pragma unroll
            for (int r = 0; r < 4; ++r) {
                double s = acc[i][j][r];
                float hi = (float)s;
                float lo = (float)(s - (double)hi);
                const size_t off = (size_t)(wo + i * 16 + drow[r]) * T_DIM + col;
                ohi[off] = hi; olo[off] = lo;
            }
        }
}

// ---------------- scan: f64 LIF, in place over hi (proven) ----------------
__global__ __launch_bounds__(256) void spk_scan_f64_kernel(
    float* __restrict__ hi, const float* __restrict__ lo)
{
    const int TC = 16;
    __shared__ float thi[256][TC + 1];
    __shared__ float tlo[256][TC + 1];
    const int tid = threadIdx.x;
    const size_t row0 = (size_t)blockIdx.x * 256;

    double mem = 0.0;
    for (int t0 = 0; t0 < T_DIM; t0 += TC) {
        #pragma unroll
        for (int p = 0; p < 4; ++p) {
            int id = tid + p * 256;
            int r = id / 4, c = (id % 4) * 4;
            size_t g = (row0 + r) * T_DIM + t0 + c;
            float4 vh = *(const float4*)&hi[g];
            thi[r][c] = vh.x; thi[r][c+1] = vh.y; thi[r][c+2] = vh.z; thi[r][c+3] = vh.w;
            float4 vl = *(const float4*)&lo[g];
            tlo[r][c] = vl.x; tlo[r][c+1] = vl.y; tlo[r][c+2] = vl.z; tlo[r][c+3] = vl.w;
        }
        __syncthreads();
        float spk[TC];
        #pragma unroll
        for (int t = 0; t < TC; ++t) {
            double s = (double)thi[tid][t] + (double)tlo[tid][t];
            double reset = (mem > 1.0) ? 1.0 : 0.0;
            mem = 0.9 * mem + s - reset;
            spk[t] = ((mem - 1.0) > 0.0) ? 1.0f : 0.0f;
        }
        __syncthreads();
        #pragma unroll
        for (int t = 0; t < TC; ++t) thi[tid][t] = spk[t];
        __syncthreads();
        #pragma unroll
        for (int p = 0; p < 4; ++p) {
            int id = tid + p * 256;
            int r = id / 4, c = (id % 4) * 4;
            float4 v = make_float4(thi[r][c], thi[r][c+1], thi[r][c+2], thi[r][c+3]);
            *(float4*)&hi[(row0 + r) * T_DIM + t0 + c] = v;
        }
        __syncthreads();
    }
}

extern "C" void kernel_launch(void* const* d_in, const int* in_sizes, int n_in,
                              void* d_out, int out_size, void* d_ws, size_t ws_size,
                              hipStream_t stream)
{
    const float* x = (const float*)d_in[0];
    const float* W = (const float*)d_in[1];
    float* hi = (float*)d_out;
    char* ws = (char*)d_ws;
    float* lo = (float*)(ws + LO_OFF);

    if (ws_size >= WS_NEED) {
        signed char* wsl = (signed char*)(ws + WSL_OFF);
        signed char* xsl = (signed char*)(ws + XSL_OFF);
        int* alpha = (int*)(ws + AL_OFF);
        int* beta  = (int*)(ws + BE_OFF);
        float* part = (float*)(ws + PART_OFF);

        k_beta_part<<<dim3(16, B_DIM), dim3(256), 0, stream>>>(x, part);
        k_beta<<<dim3(B_DIM), dim3(256), 0, stream>>>(part, beta);
        k_slice_w<<<dim3(OUT_DIM), dim3(256), 0, stream>>>(W, wsl, alpha);
        k_slice_x<<<dim3(4, 16, B_DIM), dim3(256), 0, stream>>>(x, beta, xsl);
        k_oz_gemm<<<dim3(4, 16, B_DIM), dim3(256), 0, stream>>>(wsl, xsl, alpha, beta, hi, lo);
    } else {
        spk_gemm_mfma64p_kernel<<<dim3(2, 8, B_DIM), dim3(256), 0, stream>>>(x, W, hi, lo);
    }
    spk_scan_f64_kernel<<<dim3((B_DIM * OUT_DIM) / 256), dim3(256), 0, stream>>>(hi, lo);
}

// Round 8
// 554.072 us; speedup vs baseline: 6.7431x; 1.0351x over previous
//
#include <hip/hip_runtime.h>

// B=64, IN=1024, OUT=1024, T=256
// syn[b,o,t] = sum_i W[o,i]*x[b,i,t]; spikes via f64 LIF scan.
//
// R8: Ozaki int8 (6 signed 7-bit digits, exact i32 MFMA groups, p+q<=6).
// NEW: wsl/xsl stored in MFMA FRAGMENT ORDER [p][tile32][ks][lane][16B]
// using the R7-verified i8 operand lane map (row/col=lane&31, khalf=lane>>5,
// 16 contiguous k-bytes). GEMM staging: coalesced 1KB/wave global loads,
// tid*16 LDS writes, lane*16 LDS reads -> zero bank conflicts (R7: 2.5e7
// conflicts from 4-way row-stride reads). LDS 60->48 KB.
// D-placement decoded by runtime probes (R6 technique). 6-digit error
// ~2e-11 in mem -> ~5e-5 expected spike flips. Fallback: R6 f64-MFMA path.

#define B_DIM 64
#define IN_DIM 1024
#define OUT_DIM 1024
#define T_DIM 256

typedef int v4i __attribute__((ext_vector_type(4)));
typedef int v16i __attribute__((ext_vector_type(16)));
typedef double v4d __attribute__((ext_vector_type(4)));

// ---------------- workspace layout (bytes) ----------------
#define LO_OFF   0ull                    // 67108864  f32 syn_lo
#define WSL_OFF  67108864ull             // 6291456   i8 W frags [6][o32:32][ks:32][lane:64][16]
#define XSL_OFF  73400320ull             // 100663296 i8 x frags [6][b:64][t32:8][ks:32][lane:64][16]
#define AL_OFF   174063616ull            // 4096      i32 alpha_e[1024]
#define BE_OFF   174067712ull            // 65536     i32 beta_e[64][256]
#define PART_OFF 174133248ull            // 1048576   f32 partial maxes [64][16][256]
#define WS_NEED  175181824ull

// ---------------- K1a: partial column maxes (proven) ----------------
__global__ __launch_bounds__(256) void k_beta_part(const float* __restrict__ x,
                                                   float* __restrict__ part)
{
    const int ic = blockIdx.x;   // i chunk 0..15
    const int b  = blockIdx.y;
    const int t  = threadIdx.x;
    const float* p = x + ((size_t)b * IN_DIM + ic * 64) * T_DIM + t;
    float m = 0.f;
    #pragma unroll 4
    for (int i = 0; i < 64; ++i) m = fmaxf(m, fabsf(p[(size_t)i * T_DIM]));
    part[((size_t)b * 16 + ic) * T_DIM + t] = m;
}

// ---------------- K1b: beta exponents (proven) ----------------
__global__ __launch_bounds__(256) void k_beta(const float* __restrict__ part,
                                              int* __restrict__ beta_e)
{
    const int b = blockIdx.x, t = threadIdx.x;
    float m = 0.f;
    #pragma unroll
    for (int ic = 0; ic < 16; ++ic)
        m = fmaxf(m, part[((size_t)b * 16 + ic) * T_DIM + t]);
    int e = 0;
    if (m > 0.f) frexpf(m, &e);   // |x|/2^e < 1
    beta_e[b * T_DIM + t] = e;
}

// ---------------- K2: slice x -> fragment order ----------------
// Block (tb: t-tile64, ib: i-tile64, b). Thread -> one 16B unit per slice:
// t32l=tid>>7, ksl=(tid>>6)&1, lane=tid&63;
// t_local = t32l*32+(lane&31), k_local = ksl*32+(lane>>5)*16 (+j).
__global__ __launch_bounds__(256) void k_slice_x(const float* __restrict__ x,
    const int* __restrict__ beta_e, signed char* __restrict__ xsl)
{
    __shared__ float ft[64][65];
    const int tb = blockIdx.x;    // 0..3
    const int ib = blockIdx.y;    // 0..15
    const int b  = blockIdx.z;
    const int tid = threadIdx.x;
    const int t0 = tb * 64, i0 = ib * 64;
    #pragma unroll
    for (int p = 0; p < 16; ++p) {
        int id = tid + p * 256;
        int il = id >> 6, tl = id & 63;
        ft[il][tl] = x[((size_t)b * IN_DIM + i0 + il) * T_DIM + t0 + tl];
    }
    __syncthreads();

    const int t32l = tid >> 7;
    const int ksl  = (tid >> 6) & 1;
    const int lane = tid & 63;
    const int t_local = t32l * 32 + (lane & 31);
    const int k_local = ksl * 32 + (lane >> 5) * 16;
    const int e = beta_e[b * T_DIM + t0 + t_local];

    signed char dig[16][6];
    #pragma unroll
    for (int j = 0; j < 16; ++j) {
        double r = ldexp((double)ft[k_local + j][t_local], -e);  // exact dyadic
        #pragma unroll
        for (int p = 0; p < 6; ++p) {
            r *= 128.0;              // exact
            double d = trunc(r);     // digit in [-127,127]
            r -= d;                  // exact
            dig[j][p] = (signed char)(int)d;
        }
    }
    #pragma unroll
    for (int p = 0; p < 6; ++p) {
        int w[4];
        #pragma unroll
        for (int g = 0; g < 4; ++g)
            w[g] = (dig[4*g][p] & 0xff) | ((dig[4*g+1][p] & 0xff) << 8) |
                   ((dig[4*g+2][p] & 0xff) << 16) | ((dig[4*g+3][p] & 0xff) << 24);
        const size_t base =
            ((((size_t)p * B_DIM + b) * 8 + (tb * 2 + t32l)) * 32 + (ib * 2 + ksl)) * 1024
            + lane * 16;
        *(v4i*)&xsl[base] = (v4i){w[0], w[1], w[2], w[3]};
    }
}

// ---------------- K3: alpha + slice W -> fragment order ----------------
// Grid 1024 (o). Phase 1: row max + cache row in LDS. Phase 2: threads 0..63,
// unit ks=tid>>1, khalf=tid&1 -> k0 = 16*tid; lane = (o&31)+32*khalf.
__global__ __launch_bounds__(256) void k_slice_w(const float* __restrict__ W,
    signed char* __restrict__ wsl, int* __restrict__ alpha_e)
{
    __shared__ float red[256];
    __shared__ float wrow[1024];
    __shared__ int se;
    const int o = blockIdx.x, tid = threadIdx.x;
    float4 v = *(const float4*)&W[(size_t)o * IN_DIM + tid * 4];
    *(float4*)&wrow[tid * 4] = v;
    float m = fmaxf(fmaxf(fabsf(v.x), fabsf(v.y)), fmaxf(fabsf(v.z), fabsf(v.w)));
    red[tid] = m; __syncthreads();
    for (int s = 128; s > 0; s >>= 1) {
        if (tid < s) red[tid] = fmaxf(red[tid], red[tid + s]);
        __syncthreads();
    }
    if (tid == 0) { int e = 0; if (red[0] > 0.f) frexpf(red[0], &e); se = e; alpha_e[o] = e; }
    __syncthreads();
    if (tid >= 64) return;
    const int e = se;
    const int ks = tid >> 1, khalf = tid & 1;
    const int k0 = tid * 16;
    const int lane = (o & 31) + 32 * khalf;

    signed char dig[16][6];
    #pragma unroll
    for (int j = 0; j < 16; ++j) {
        double r = ldexp((double)wrow[k0 + j], -e);
        #pragma unroll
        for (int p = 0; p < 6; ++p) {
            r *= 128.0; double d = trunc(r); r -= d;
            dig[j][p] = (signed char)(int)d;
        }
    }
    #pragma unroll
    for (int p = 0; p < 6; ++p) {
        int w[4];
        #pragma unroll
        for (int g = 0; g < 4; ++g)
            w[g] = (dig[4*g][p] & 0xff) | ((dig[4*g+1][p] & 0xff) << 8) |
                   ((dig[4*g+2][p] & 0xff) << 16) | ((dig[4*g+3][p] & 0xff) << 24);
        const size_t base =
            (((size_t)p * 32 + (o >> 5)) * 32 + ks) * 1024 + lane * 16;
        *(v4i*)&wsl[base] = (v4i){w[0], w[1], w[2], w[3]};
    }
}

// ---------------- K4: Ozaki i8 MFMA GEMM (fragment-ordered) ----------------
// Block 64(o)x64(t), 4 waves 2x2 of 32x32. BK=64 (2 MFMA k-steps).
// LDS: [p:6][half32:2][ksl:2][lane:64][16B] per matrix = 24 KB each.
__global__ __launch_bounds__(256, 2) void k_oz_gemm(
    const signed char* __restrict__ wsl, const signed char* __restrict__ xsl,
    const int* __restrict__ alpha_e, const int* __restrict__ beta_e,
    float* __restrict__ syn_hi, float* __restrict__ syn_lo)
{
    __shared__ __align__(16) signed char As[24576];
    __shared__ __align__(16) signed char Bs[24576];

    const int tid = threadIdx.x;
    const int lane = tid & 63, wave = tid >> 6;
    const int tb = blockIdx.x;   // 0..3
    const int ob = blockIdx.y;   // 0..15
    const int b  = blockIdx.z;
    const int o0 = ob * 64, t0 = tb * 64;
    const int woh = wave >> 1;   // o half (0/1)
    const int wth = wave & 1;    // t half (0/1)

    v16i acc[7];
    #pragma unroll
    for (int s = 0; s < 7; ++s)
        acc[s] = (v16i){0,0,0,0,0,0,0,0,0,0,0,0,0,0,0,0};

    // Staging: thread stages unit u = tid + 256*j (j = slice): LDS off u*16.
    // Global A: ((j*32 + 2*ob + h)*32 + 2*kt + ksl)*1024 + lane*16
    // Global B: (((j*64 + b)*8 + 2*tb + h)*32 + 2*kt + ksl)*1024 + lane*16
    // where h = (tid>>7)&1, ksl = (tid>>6)&1 (== bits of u&255).
    const int sh  = (tid >> 7) & 1;
    const int sks = (tid >> 6) & 1;
    const size_t abase = (((size_t)(2 * ob + sh)) * 32 + sks) * 1024 + (tid & 63) * 16;
    const size_t bbase = ((((size_t)b) * 8 + (2 * tb + sh)) * 32 + sks) * 1024 + (tid & 63) * 16;
    const int ldso = tid * 16;

    v4i pa[6], pb[6];
    #pragma unroll
    for (int j = 0; j < 6; ++j) {   // preload kt=0
        pa[j] = *(const v4i*)(wsl + ((size_t)j << 20) + abase);
        pb[j] = *(const v4i*)(xsl + ((size_t)j << 24) + bbase);
    }

    for (int kt = 0; kt < 16; ++kt) {
        #pragma unroll
        for (int j = 0; j < 6; ++j) {
            *(v4i*)(As + j * 4096 + ldso) = pa[j];
            *(v4i*)(Bs + j * 4096 + ldso) = pb[j];
        }
        if (kt < 15) {
            #pragma unroll
            for (int j = 0; j < 6; ++j) {
                pa[j] = *(const v4i*)(wsl + ((size_t)j << 20) + abase + (kt + 1) * 2048);
                pb[j] = *(const v4i*)(xsl + ((size_t)j << 24) + bbase + (kt + 1) * 2048);
            }
        }
        __syncthreads();

        #pragma unroll
        for (int ksl = 0; ksl < 2; ++ksl) {
            const int fro = woh * 2048 + ksl * 1024 + lane * 16;
            const int frt = wth * 2048 + ksl * 1024 + lane * 16;
            v4i bf[6];
            #pragma unroll
            for (int q = 0; q < 6; ++q)
                bf[q] = *(const v4i*)(Bs + q * 4096 + frt);
            #pragma unroll
            for (int p = 0; p < 6; ++p) {
                v4i af = *(const v4i*)(As + p * 4096 + fro);
                #pragma unroll
                for (int q = 0; q < 6; ++q) {
                    if (p + q <= 6)
                        acc[p + q] = __builtin_amdgcn_mfma_i32_32x32x32_i8(
                            af, bf[q], acc[p + q], 0, 0, 0);
                }
            }
        }
        __syncthreads();
    }

    // Runtime D-placement probes (R6/R7 technique).
    const int lr = lane & 31;
    const int rv = (lr + 1) * 0x01010101;
    const v4i pav  = {rv, rv, rv, rv};
    const v4i onev = {0x01010101, 0x01010101, 0x01010101, 0x01010101};
    const v16i z = (v16i){0,0,0,0,0,0,0,0,0,0,0,0,0,0,0,0};
    v16i d1 = __builtin_amdgcn_mfma_i32_32x32x32_i8(pav, onev, z, 0, 0, 0);
    v16i d2 = __builtin_amdgcn_mfma_i32_32x32x32_i8(onev, pav, z, 0, 0, 0);

    const int col = (d2[0] >> 5) - 1;            // 0..31 within tile
    const int gt = t0 + wth * 32 + col;
    const int eb = beta_e[b * T_DIM + gt];
    float* ohi = syn_hi + ((size_t)b * OUT_DIM + o0) * T_DIM + gt;
    float* olo = syn_lo + ((size_t)b * OUT_DIM + o0) * T_DIM + gt;

    const double C0 = 0x1p-14, C1 = 0x1p-21, C2 = 0x1p-28, C3 = 0x1p-35,
                 C4 = 0x1p-42, C5 = 0x1p-49, C6 = 0x1p-56;
    #pragma unroll
    for (int r = 0; r < 16; ++r) {
        const int row = (d1[r] >> 5) - 1;        // 0..31 within tile
        const int go = woh * 32 + row;
        const int ea = alpha_e[o0 + go];
        double v = (double)acc[0][r] * C0 + (double)acc[1][r] * C1 +
                   (double)acc[2][r] * C2 + (double)acc[3][r] * C3 +
                   (double)acc[4][r] * C4 + (double)acc[5][r] * C5 +
                   (double)acc[6][r] * C6;
        double syn = ldexp(v, ea + eb);
        float hi = (float)syn;
        float lo = (float)(syn - (double)hi);
        ohi[(size_t)go * T_DIM] = hi;
        olo[(size_t)go * T_DIM] = lo;
    }
}

// ---------------- Fallback GEMM: R6 f64-MFMA with probes (proven) ----------
#define BM 128
#define BN 128
#define BK 16
#define LDA 130

__global__ __launch_bounds__(256, 2) void spk_gemm_mfma64p_kernel(
    const float* __restrict__ x, const float* __restrict__ W,
    float* __restrict__ syn_hi, float* __restrict__ syn_lo)
{
    const int tid  = threadIdx.x;
    const int lane = tid & 63;
    const int wave = tid >> 6;
    const int tb = blockIdx.x, ob = blockIdx.y, b = blockIdx.z;

    __shared__ __align__(16) double As[BK][LDA];
    __shared__ __align__(16) double Bs[BK][LDA];

    const v4d zz = {0.0, 0.0, 0.0, 0.0};
    v4d d1 = __builtin_amdgcn_mfma_f64_16x16x4f64((double)lane, 1.0, zz, 0, 0, 0);
    v4d d2 = __builtin_amdgcn_mfma_f64_16x16x4f64(1.0, (double)lane, zz, 0, 0, 0);
    const bool a_h1 = (((int)d1[0] & 3) == 0);
    const bool b_h1 = (((int)d2[0] & 3) == 0);
    int drow[4];
    #pragma unroll
    for (int r = 0; r < 4; ++r) {
        const int v = (int)d1[r];
        drow[r] = (a_h1 ? (v - 96) >> 2 : (v - 6) >> 4) & 15;
    }
    const int am = a_h1 ? (lane & 15) : (lane >> 2);
    const int ak = a_h1 ? (lane >> 4) : (lane & 3);
    const int bn = b_h1 ? (lane & 15) : (lane >> 2);
    const int bk = b_h1 ? (lane >> 4) : (lane & 3);
    const int dcol = lane & 15;

    const int o0 = ob * BM, t0 = tb * BN;
    const float* Wp = W + (size_t)o0 * IN_DIM;
    const float* xp = x + (size_t)b * IN_DIM * T_DIM + t0;
    const int wo = (wave >> 1) * 64, wt = (wave & 1) * 64;

    v4d acc[4][4];
    #pragma unroll
    for (int i = 0; i < 4; ++i)
        #pragma unroll
        for (int j = 0; j < 4; ++j) acc[i][j] = zz;

    const int ar0 = tid / 4, ac = (tid % 4) * 4;
    const int bkr0 = tid / 32, btc = (tid % 32) * 4;

    float4 pa[2], pb[2];
    #pragma unroll
    for (int p = 0; p < 2; ++p) {
        pa[p] = *(const float4*)&Wp[(size_t)(ar0 + p * 64) * IN_DIM + ac];
        pb[p] = *(const float4*)&xp[(size_t)(bkr0 + p * 8) * T_DIM + btc];
    }

    for (int k0 = 0; k0 < IN_DIM; k0 += BK) {
        #pragma unroll
        for (int p = 0; p < 2; ++p) {
            const int r = ar0 + p * 64;
            As[ac + 0][r] = (double)pa[p].x; As[ac + 1][r] = (double)pa[p].y;
            As[ac + 2][r] = (double)pa[p].z; As[ac + 3][r] = (double)pa[p].w;
            const int kr = bkr0 + p * 8;
            Bs[kr][btc + 0] = (double)pb[p].x; Bs[kr][btc + 1] = (double)pb[p].y;
            Bs[kr][btc + 2] = (double)pb[p].z; Bs[kr][btc + 3] = (double)pb[p].w;
        }
        if (k0 + BK < IN_DIM) {
            #pragma unroll
            for (int p = 0; p < 2; ++p) {
                pa[p] = *(const float4*)&Wp[(size_t)(ar0 + p * 64) * IN_DIM + k0 + BK + ac];
                pb[p] = *(const float4*)&xp[(size_t)(bkr0 + p * 8 + k0 + BK) * T_DIM + btc];
            }
        }
        __syncthreads();
        #pragma unroll
        for (int kk = 0; kk < 4; ++kk) {
            const int kra = kk * 4 + ak, krb = kk * 4 + bk;
            double a[4], bb[4];
            #pragma unroll
            for (int i = 0; i < 4; ++i) a[i] = As[kra][wo + i * 16 + am];
            #pragma unroll
            for (int j = 0; j < 4; ++j) bb[j] = Bs[krb][wt + j * 16 + bn];
            #pragma unroll
            for (int i = 0; i < 4; ++i)
                #pragma unroll
                for (int j = 0; j < 4; ++j)
                    acc[i][j] = __builtin_amdgcn_mfma_f64_16x16x4f64(a[i], bb[j], acc[i][j], 0, 0, 0);
        }
        __syncthreads();
    }

    float* ohi = syn_hi + ((size_t)b * OUT_DIM + o0) * T_DIM + t0;
    float* olo = syn_lo + ((size_t)b * OUT_DIM + o0) * T_DIM + t0;
    #pragma unroll
    for (int i = 0; i < 4; ++i)
        #pragma unroll
        for (int j = 0; j < 4; ++j) {
            const int col = wt + j * 16 + dcol;
            #pragma unroll
            for (int r = 0; r < 4; ++r) {
                double s = acc[i][j][r];
                float hi = (float)s;
                float lo = (float)(s - (double)hi);
                const size_t off = (size_t)(wo + i * 16 + drow[r]) * T_DIM + col;
                ohi[off] = hi; olo[off] = lo;
            }
        }
}

// ---------------- scan: f64 LIF, in place over hi (proven) ----------------
__global__ __launch_bounds__(256) void spk_scan_f64_kernel(
    float* __restrict__ hi, const float* __restrict__ lo)
{
    const int TC = 16;
    __shared__ float thi[256][TC + 1];
    __shared__ float tlo[256][TC + 1];
    const int tid = threadIdx.x;
    const size_t row0 = (size_t)blockIdx.x * 256;

    double mem = 0.0;
    for (int t0 = 0; t0 < T_DIM; t0 += TC) {
        #pragma unroll
        for (int p = 0; p < 4; ++p) {
            int id = tid + p * 256;
            int r = id / 4, c = (id % 4) * 4;
            size_t g = (row0 + r) * T_DIM + t0 + c;
            float4 vh = *(const float4*)&hi[g];
            thi[r][c] = vh.x; thi[r][c+1] = vh.y; thi[r][c+2] = vh.z; thi[r][c+3] = vh.w;
            float4 vl = *(const float4*)&lo[g];
            tlo[r][c] = vl.x; tlo[r][c+1] = vl.y; tlo[r][c+2] = vl.z; tlo[r][c+3] = vl.w;
        }
        __syncthreads();
        float spk[TC];
        #pragma unroll
        for (int t = 0; t < TC; ++t) {
            double s = (double)thi[tid][t] + (double)tlo[tid][t];
            double reset = (mem > 1.0) ? 1.0 : 0.0;
            mem = 0.9 * mem + s - reset;
            spk[t] = ((mem - 1.0) > 0.0) ? 1.0f : 0.0f;
        }
        __syncthreads();
        #pragma unroll
        for (int t = 0; t < TC; ++t) thi[tid][t] = spk[t];
        __syncthreads();
        #pragma unroll
        for (int p = 0; p < 4; ++p) {
            int id = tid + p * 256;
            int r = id / 4, c = (id % 4) * 4;
            float4 v = make_float4(thi[r][c], thi[r][c+1], thi[r][c+2], thi[r][c+3]);
            *(float4*)&hi[(row0 + r) * T_DIM + t0 + c] = v;
        }
        __syncthreads();
    }
}

extern "C" void kernel_launch(void* const* d_in, const int* in_sizes, int n_in,
                              void* d_out, int out_size, void* d_ws, size_t ws_size,
                              hipStream_t stream)
{
    const float* x = (const float*)d_in[0];
    const float* W = (const float*)d_in[1];
    float* hi = (float*)d_out;
    char* ws = (char*)d_ws;
    float* lo = (float*)(ws + LO_OFF);

    if (ws_size >= WS_NEED) {
        signed char* wsl = (signed char*)(ws + WSL_OFF);
        signed char* xsl = (signed char*)(ws + XSL_OFF);
        int* alpha = (int*)(ws + AL_OFF);
        int* beta  = (int*)(ws + BE_OFF);
        float* part = (float*)(ws + PART_OFF);

        k_beta_part<<<dim3(16, B_DIM), dim3(256), 0, stream>>>(x, part);
        k_beta<<<dim3(B_DIM), dim3(256), 0, stream>>>(part, beta);
        k_slice_w<<<dim3(OUT_DIM), dim3(256), 0, stream>>>(W, wsl, alpha);
        k_slice_x<<<dim3(4, 16, B_DIM), dim3(256), 0, stream>>>(x, beta, xsl);
        k_oz_gemm<<<dim3(4, 16, B_DIM), dim3(256), 0, stream>>>(wsl, xsl, alpha, beta, hi, lo);
    } else {
        spk_gemm_mfma64p_kernel<<<dim3(2, 8, B_DIM), dim3(256), 0, stream>>>(x, W, hi, lo);
    }
    spk_scan_f64_kernel<<<dim3((B_DIM * OUT_DIM) / 256), dim3(256), 0, stream>>>(hi, lo);
}